// Round 7
// baseline (2112.222 us; speedup 1.0000x reference)
//
#include <hip/hip_runtime.h>

typedef unsigned short u16;
typedef __attribute__((ext_vector_type(8))) short short8;
typedef __attribute__((ext_vector_type(4))) float floatx4;
typedef __attribute__((ext_vector_type(2))) float floatx2;

#define N_NODESC 100000
#define N_EDGESC 1600000
#define N_GRAPHSC 256
#define F_INC 128
#define HDIM 256
#define GEMM_BX 782
#define GEMM_NBLK (GEMM_BX * 2)
#define GEMM_PAD 1568                  // 16*98 paired-swizzle launch (4 idle)
#define RX_NBLK 512
#define RX_EPB (N_EDGESC / RX_NBLK)   // 3125 exact
#define RX_NBUCKET 196                 // ceil(100000/512)

// async global->LDS DMA, 16B per lane, dest = wave-uniform base + lane*16
#define GLDS16(g, l) __builtin_amdgcn_global_load_lds( \
    (const __attribute__((address_space(1))) unsigned int*)(g), \
    (__attribute__((address_space(3))) unsigned int*)(l), 16, 0, 0)

__device__ __forceinline__ float bf2f(u16 u) {
    union { unsigned int i; float f; } v; v.i = ((unsigned int)u) << 16; return v.f;
}
__device__ __forceinline__ u16 f2bf(float f) {
    union { float f; unsigned int i; } v; v.f = f;
    unsigned int b = v.i;
    b += 0x7fffu + ((b >> 16) & 1u);
    return (u16)(b >> 16);
}
__device__ __forceinline__ void up8(uint4 v, float* f) {
    f[0] = bf2f((u16)(v.x & 0xffff)); f[1] = bf2f((u16)(v.x >> 16));
    f[2] = bf2f((u16)(v.y & 0xffff)); f[3] = bf2f((u16)(v.y >> 16));
    f[4] = bf2f((u16)(v.z & 0xffff)); f[5] = bf2f((u16)(v.z >> 16));
    f[6] = bf2f((u16)(v.w & 0xffff)); f[7] = bf2f((u16)(v.w >> 16));
}
__device__ __forceinline__ unsigned int pk2(float a, float b) {
    return (unsigned int)f2bf(a) | ((unsigned int)f2bf(b) << 16);
}
// accumulate 16 fp8(e4m3) from uint4 into 8 packed float2 accumulators (v_pk_add_f32)
__device__ __forceinline__ void accv(uint4 v, floatx2* a) {
    a[0] += __builtin_amdgcn_cvt_pk_f32_fp8(v.x, false);
    a[1] += __builtin_amdgcn_cvt_pk_f32_fp8(v.x, true);
    a[2] += __builtin_amdgcn_cvt_pk_f32_fp8(v.y, false);
    a[3] += __builtin_amdgcn_cvt_pk_f32_fp8(v.y, true);
    a[4] += __builtin_amdgcn_cvt_pk_f32_fp8(v.z, false);
    a[5] += __builtin_amdgcn_cvt_pk_f32_fp8(v.z, true);
    a[6] += __builtin_amdgcn_cvt_pk_f32_fp8(v.w, false);
    a[7] += __builtin_amdgcn_cvt_pk_f32_fp8(v.w, true);
}

// ---------- fused prep: 5 weight transposes + x dual-convert + ticket reset ----------
__device__ __forceinline__ void wcat_one(const float* __restrict__ Wl,
                                         const float* __restrict__ Wr,
                                         int K1, int K, u16* __restrict__ out, int idx) {
    int c = idx / K, k = idx - c * K;
    float v = (k < K1) ? Wl[k * 256 + c] : Wr[(k - K1) * 256 + c];
    out[idx] = f2bf(v);
}
__global__ __launch_bounds__(256) void k_prep(
    const float* __restrict__ Wl1, const float* __restrict__ Wr1,
    const float* __restrict__ Wl2, const float* __restrict__ Wr2,
    const float* __restrict__ Wl3, const float* __restrict__ Wr3,
    const float* __restrict__ Wl4, const float* __restrict__ Wr4,
    const float* __restrict__ resW, const float* __restrict__ x,
    u16* __restrict__ Wt1, u16* __restrict__ Wt2, u16* __restrict__ Wt3,
    u16* __restrict__ Wt4, u16* __restrict__ Rt,
    u16* __restrict__ xb, unsigned char* __restrict__ xb8,
    int* __restrict__ tickets) {
    const int b = blockIdx.x;
    const int t = threadIdx.x;
    if (b == 0 && t < 16) tickets[t] = 0;
    if (b < 256) {                       // Wt1: 256x256
        wcat_one(Wl1, Wr1, 128, 256, Wt1, b * 256 + t);
    } else if (b < 768) {                // Wt2: 256x512
        wcat_one(Wl2, Wr2, 256, 512, Wt2, (b - 256) * 256 + t);
    } else if (b < 1280) {               // Wt3
        wcat_one(Wl3, Wr3, 256, 512, Wt3, (b - 768) * 256 + t);
    } else if (b < 1792) {               // Wt4
        wcat_one(Wl4, Wr4, 256, 512, Wt4, (b - 1280) * 256 + t);
    } else if (b < 1920) {               // Rt: 256x128 (K1=K=128, Wr never read)
        wcat_one(resW, resW, 128, 128, Rt, (b - 1792) * 256 + t);
    } else {                             // f2both: 6250 blocks exact
        const int i = (b - 1920) * 256 + t;
        float4 v0 = ((const float4*)x)[2 * i];
        float4 v1 = ((const float4*)x)[2 * i + 1];
        ((uint4*)xb)[i] = make_uint4(pk2(v0.x, v0.y), pk2(v0.z, v0.w),
                                     pk2(v1.x, v1.y), pk2(v1.z, v1.w));
        unsigned int wlo = __builtin_amdgcn_cvt_pk_fp8_f32(v0.x, v0.y, 0, false);
        wlo = __builtin_amdgcn_cvt_pk_fp8_f32(v0.z, v0.w, wlo, true);
        unsigned int whi = __builtin_amdgcn_cvt_pk_fp8_f32(v1.x, v1.y, 0, false);
        whi = __builtin_amdgcn_cvt_pk_fp8_f32(v1.z, v1.w, whi, true);
        ((uint2*)xb8)[i] = make_uint2(wlo, whi);
    }
}

// ========== CSR build via bucketed counting sort — LDS atomics only ==========
__global__ __launch_bounds__(256) void k_rxcount(const int* __restrict__ dst,
                                                 int* __restrict__ bhist) {
    __shared__ int h[RX_NBUCKET];
    for (int i = threadIdx.x; i < RX_NBUCKET; i += 256) h[i] = 0;
    __syncthreads();
    const int e0 = blockIdx.x * RX_EPB;
    for (int e = e0 + threadIdx.x; e < e0 + RX_EPB; e += 256)
        atomicAdd(&h[dst[e] >> 9], 1);
    __syncthreads();
    for (int i = threadIdx.x; i < RX_NBUCKET; i += 256)
        bhist[blockIdx.x * RX_NBUCKET + i] = h[i];
}

__global__ void k_rxscan1(int* __restrict__ bhist, int* __restrict__ btot) {
    const int k = blockIdx.x;   // bucket
    const int t = threadIdx.x;  // 0..63
    int v[RX_NBLK / 64];
    int s = 0;
#pragma unroll
    for (int i = 0; i < RX_NBLK / 64; ++i) {
        v[i] = bhist[(t * (RX_NBLK / 64) + i) * RX_NBUCKET + k];
        s += v[i];
    }
    int incl = s;
#pragma unroll
    for (int off = 1; off < 64; off <<= 1) {
        int u = __shfl_up(incl, off);
        if (t >= off) incl += u;
    }
    int run = incl - s;  // exclusive
#pragma unroll
    for (int i = 0; i < RX_NBLK / 64; ++i) {
        bhist[(t * (RX_NBLK / 64) + i) * RX_NBUCKET + k] = run;
        run += v[i];
    }
    if (t == 63) btot[k] = run;
}

__global__ void k_rxscan2(const int* __restrict__ btot, int* __restrict__ bex,
                          int* __restrict__ cptr, const int* __restrict__ batch,
                          int* __restrict__ gptr) {
    __shared__ int ts[256];
    int t = threadIdx.x;
    int v = (t < RX_NBUCKET) ? btot[t] : 0;
    ts[t] = v;
    __syncthreads();
    for (int off = 1; off < 256; off <<= 1) {
        int u = (t >= off) ? ts[t - off] : 0;
        __syncthreads();
        ts[t] += u;
        __syncthreads();
    }
    if (t < RX_NBUCKET) bex[t] = ts[t] - v;
    if (t == RX_NBUCKET - 1) bex[RX_NBUCKET] = ts[t];
    if (t == 0) cptr[N_NODESC] = N_EDGESC;
    {
        int lo = 0, hi = N_NODESC;
        while (lo < hi) {
            int mid = (lo + hi) >> 1;
            if (batch[mid] < t) lo = mid + 1; else hi = mid;
        }
        gptr[t] = lo;
        if (t == 0) gptr[N_GRAPHSC] = N_NODESC;
    }
}

__global__ __launch_bounds__(256) void k_rxscatter(
    const int* __restrict__ src, const int* __restrict__ dst,
    const int* __restrict__ bhist, const int* __restrict__ bex,
    int2* __restrict__ ebuf) {
    __shared__ int lb[RX_NBUCKET];
    for (int i = threadIdx.x; i < RX_NBUCKET; i += 256)
        lb[i] = bex[i] + bhist[blockIdx.x * RX_NBUCKET + i];
    __syncthreads();
    const int e0 = blockIdx.x * RX_EPB;
    for (int e = e0 + threadIdx.x; e < e0 + RX_EPB; e += 256) {
        int d = dst[e];
        int s = src[e];
        int pos = atomicAdd(&lb[d >> 9], 1);
        ebuf[pos] = make_int2(s, d);
    }
}

__global__ __launch_bounds__(256) void k_rxcsr(
    const int2* __restrict__ ebuf, const int* __restrict__ bex,
    int* __restrict__ cptr, float* __restrict__ dinv, int* __restrict__ adj) {
    __shared__ int cnt[512];
    __shared__ int excl[512];
    __shared__ int ts[256];
    const int k = blockIdx.x;
    const int nb0 = k * 512;
    const int ebase = bex[k], eend = bex[k + 1];
    const int t = threadIdx.x;
    for (int i = t; i < 512; i += 256) cnt[i] = 0;
    __syncthreads();
    for (int e = ebase + t; e < eend; e += 256)
        atomicAdd(&cnt[ebuf[e].y - nb0], 1);
    __syncthreads();
    {
        int c0 = cnt[2 * t], c1 = cnt[2 * t + 1];
        int ms = c0 + c1;
        ts[t] = ms;
        __syncthreads();
        for (int off = 1; off < 256; off <<= 1) {
            int u = (t >= off) ? ts[t - off] : 0;
            __syncthreads();
            ts[t] += u;
            __syncthreads();
        }
        int ex = ts[t] - ms;
        excl[2 * t] = ex;
        excl[2 * t + 1] = ex + c0;
        int n0 = nb0 + 2 * t, n1 = n0 + 1;
        if (n0 < N_NODESC) { cptr[n0] = ebase + ex; dinv[n0] = 1.f / (float)(c0 > 1 ? c0 : 1); }
        if (n1 < N_NODESC) { cptr[n1] = ebase + ex + c0; dinv[n1] = 1.f / (float)(c1 > 1 ? c1 : 1); }
    }
    __syncthreads();
    for (int i = t; i < 512; i += 256) cnt[i] = 0;
    __syncthreads();
    for (int e = ebase + t; e < eend; e += 256) {
        int2 p = ebuf[e];
        int dl = p.y - nb0;
        int r = atomicAdd(&cnt[dl], 1);
        adj[ebase + excl[dl] + r] = p.x;
    }
}

// ---------- aggregation core (v5, 4-deep, node-major fp8 — the proven 64us floor) ----------
template <int F>
__device__ __forceinline__ void agg_body(
    const unsigned char* __restrict__ q8, const int* __restrict__ cptr,
    const int* __restrict__ adj, const float* __restrict__ di,
    u16* __restrict__ out, int n, int blk) {
    constexpr int LPR = F / 16;       // lanes per node-row: 8 (F=128) or 16 (F=256)
    constexpr int NPW = 64 / LPR;     // nodes per wave
    const int lane = threadIdx.x & 63;
    const int li  = lane % LPR;
    const int grp = lane / LPR;
    const int node = (blk * 4 + ((int)threadIdx.x >> 6)) * NPW + grp;
    if (node >= n) return;
    const int p0 = cptr[node], p1 = cptr[node + 1];
    const float d = di[node];
    const unsigned char* base = q8 + (size_t)li * 16;
    floatx2 a[8];
#pragma unroll
    for (int e = 0; e < 8; ++e) a[e] = (floatx2){0.f, 0.f};

    int j = p0;
    for (; j + 4 <= p1; j += 4) {
        int i0 = adj[j], i1 = adj[j + 1], i2 = adj[j + 2], i3 = adj[j + 3];
        uint4 v0 = *(const uint4*)(base + (size_t)i0 * F);
        uint4 v1 = *(const uint4*)(base + (size_t)i1 * F);
        uint4 v2 = *(const uint4*)(base + (size_t)i2 * F);
        uint4 v3 = *(const uint4*)(base + (size_t)i3 * F);
        accv(v0, a); accv(v1, a); accv(v2, a); accv(v3, a);
    }
    for (; j < p1; ++j) {
        uint4 v0 = *(const uint4*)(base + (size_t)adj[j] * F);
        accv(v0, a);
    }

    uint4 o0 = make_uint4(pk2(a[0][0] * d, a[0][1] * d), pk2(a[1][0] * d, a[1][1] * d),
                          pk2(a[2][0] * d, a[2][1] * d), pk2(a[3][0] * d, a[3][1] * d));
    uint4 o1 = make_uint4(pk2(a[4][0] * d, a[4][1] * d), pk2(a[5][0] * d, a[5][1] * d),
                          pk2(a[6][0] * d, a[6][1] * d), pk2(a[7][0] * d, a[7][1] * d));
    u16* orow = out + (size_t)node * F + li * 16;
    *(uint4*)orow = o0;
    *(uint4*)(orow + 8) = o1;
}

template <int F>
__global__ __launch_bounds__(256) void k_aggregate5(
    const unsigned char* __restrict__ q8, const int* __restrict__ cptr,
    const int* __restrict__ adj, const float* __restrict__ di,
    u16* __restrict__ out, int n) {
    agg_body<F>(q8, cptr, adj, di, out, n, blockIdx.x);
}

// ---------- shared GEMM tile helpers (128x128, BK=64, glds staging, XOR swizzle) ----------
__device__ __forceinline__ void gemm_tile(
    const u16* __restrict__ A, int lda, int K,
    const u16* __restrict__ Bp, int bstride, int boff,
    int M, int bx, int by, u16* Al, u16* Bl, floatx4 (*acc)[4]) {
    const int t = threadIdx.x;
    const int lane = t & 63;
    const int wave = t >> 6;
    const int wr = (wave >> 1) * 64, wc = (wave & 1) * 64;
    const int quad = lane >> 4, l15 = lane & 15;
    const int rowBase = bx * 128;
    const bool fastA = (rowBase + 128 <= M);
    const int colBase = by * 128;
    const int rw = wave * 32 + (lane >> 3);
    const int lch = lane & 7;

    for (int kt = 0; kt < K; kt += 64) {
#pragma unroll
        for (int ii = 0; ii < 4; ++ii) {
            const int row = rw + ii * 8;
            const int gc = lch ^ (row & 7);
            GLDS16(Bp + (size_t)(colBase + row) * bstride + (boff + kt + gc * 8),
                   Bl + (size_t)(wave * 32 + ii * 8) * 64);
        }
        if (fastA) {
#pragma unroll
            for (int ii = 0; ii < 4; ++ii) {
                const int row = rw + ii * 8;
                const int gc = lch ^ (row & 7);
                GLDS16(A + (size_t)(rowBase + row) * lda + (kt + gc * 8),
                       Al + (size_t)(wave * 32 + ii * 8) * 64);
            }
        } else {
#pragma unroll
            for (int ii = 0; ii < 4; ++ii) {
                const int row = rw + ii * 8;
                const int gc = lch ^ (row & 7);
                const int grow = rowBase + row;
                uint4 v = make_uint4(0u, 0u, 0u, 0u);
                if (grow < M) v = *(const uint4*)(A + (size_t)grow * lda + (kt + gc * 8));
                *(uint4*)(Al + (size_t)row * 64 + lch * 8) = v;
            }
        }
        __syncthreads();
#pragma unroll
        for (int kk = 0; kk < 2; ++kk) {
            const int gcq = kk * 4 + quad;
            short8 af[4], bfr[4];
#pragma unroll
            for (int i = 0; i < 4; ++i) {
                const int row = wr + i * 16 + l15;
                af[i] = *(const short8*)(Al + (size_t)row * 64 + ((gcq ^ (row & 7)) * 8));
            }
#pragma unroll
            for (int j = 0; j < 4; ++j) {
                const int row = wc + j * 16 + l15;
                bfr[j] = *(const short8*)(Bl + (size_t)row * 64 + ((gcq ^ (row & 7)) * 8));
            }
#pragma unroll
            for (int i = 0; i < 4; ++i)
#pragma unroll
                for (int j = 0; j < 4; ++j)
                    acc[i][j] = __builtin_amdgcn_mfma_f32_16x16x32_bf16(af[i], bfr[j], acc[i][j], 0, 0, 0);
        }
        __syncthreads();
    }
}

__device__ __forceinline__ void gemm_write(
    floatx4 (*acc)[4], u16* __restrict__ C, int M, int bx, int by) {
    const int lane = threadIdx.x & 63;
    const int wave = threadIdx.x >> 6;
    const int wr = (wave >> 1) * 64, wc = (wave & 1) * 64;
    const int quad = lane >> 4, l15 = lane & 15;
    const int rowBase = bx * 128;
    const int colBase = by * 128;
#pragma unroll
    for (int i = 0; i < 4; ++i) {
#pragma unroll
        for (int r = 0; r < 4; ++r) {
            const int row = rowBase + wr + i * 16 + quad * 4 + r;
            if (row < M) {
#pragma unroll
                for (int j = 0; j < 4; ++j) {
                    const int col = colBase + wc + j * 16 + l15;
                    C[(size_t)row * HDIM + col] = f2bf(acc[i][j][r]);
                }
            }
        }
    }
}

// ---------- fused layer-1: agg<128> + res GEMM (xb@Rt -> hB); proven-free combo ----------
__global__ __launch_bounds__(256, 4) void k_agg1res(
    const unsigned char* __restrict__ q8s, const int* __restrict__ cptr,
    const int* __restrict__ adj, const float* __restrict__ di,
    u16* __restrict__ aggout, int n,
    const u16* __restrict__ A, const u16* __restrict__ Rt,
    u16* __restrict__ C, int M) {
    __shared__ __align__(16) u16 Al[128 * 64];
    __shared__ __align__(16) u16 Bl[128 * 64];
    if (blockIdx.x < 3125) {
        agg_body<128>(q8s, cptr, adj, di, aggout, n, blockIdx.x);
        return;
    }
    int bid = blockIdx.x - 3125;
    const int bx = (bid >> 4) * 8 + (bid & 7);   // paired: ids d, d+8 share bx and XCD
    const int by = (bid >> 3) & 1;
    if (bx >= GEMM_BX) return;

    floatx4 acc[4][4];
#pragma unroll
    for (int i = 0; i < 4; ++i)
#pragma unroll
        for (int j = 0; j < 4; ++j)
            acc[i][j] = (floatx4){0.f, 0.f, 0.f, 0.f};

    gemm_tile(A, 128, 128, Rt, 128, 0, M, bx, by, Al, Bl, acc);
    gemm_write(acc, C, M, bx, by);
}

// ---------- serial GEMM: C = [A1|A2] @ Wt, stats, last-block computes BN scale/shift ----
__global__ __launch_bounds__(256, 4) void k_gemm(
    const u16* __restrict__ A1, int K1,
    const u16* __restrict__ A2, int K2,
    const u16* __restrict__ Wt,
    u16* __restrict__ C, int M, float* __restrict__ statpart,
    const float* __restrict__ gg, const float* __restrict__ beta,
    float* __restrict__ sc, float* __restrict__ sh,
    float invN, int* __restrict__ ticket) {
    const int K = K1 + K2;
    __shared__ __align__(16) u16 Al[128 * 64];
    __shared__ __align__(16) u16 Bl[128 * 64];
    __shared__ float Ssum[2][128];
    __shared__ float Ssq[2][128];
    __shared__ int lastflag;
    const int id = blockIdx.x;
    const int bx = (id >> 4) * 8 + (id & 7);
    const int by = (id >> 3) & 1;
    if (bx >= GEMM_BX) return;
    const int t = threadIdx.x;
    const int lane = t & 63;
    const int wave = t >> 6;
    const int wr = (wave >> 1) * 64, wc = (wave & 1) * 64;
    const int quad = lane >> 4, l15 = lane & 15;
    const int rowBase = bx * 128;
    const bool fastA = (rowBase + 128 <= M);
    const int rw = wave * 32 + (lane >> 3);
    const int lch = lane & 7;

    floatx4 acc[4][4];
#pragma unroll
    for (int i = 0; i < 4; ++i)
#pragma unroll
        for (int j = 0; j < 4; ++j)
            acc[i][j] = (floatx4){0.f, 0.f, 0.f, 0.f};

    for (int kt = 0; kt < K; kt += 64) {
        const u16* As; int lda, kloc;
        if (kt < K1) { As = A1; lda = K1; kloc = kt; }
        else         { As = A2; lda = K2; kloc = kt - K1; }
#pragma unroll
        for (int ii = 0; ii < 4; ++ii) {
            const int row = rw + ii * 8;
            const int gc = lch ^ (row & 7);
            GLDS16(Wt + (size_t)(by * 128 + row) * K + (kt + gc * 8),
                   Bl + (size_t)(wave * 32 + ii * 8) * 64);
        }
        if (fastA) {
#pragma unroll
            for (int ii = 0; ii < 4; ++ii) {
                const int row = rw + ii * 8;
                const int gc = lch ^ (row & 7);
                GLDS16(As + (size_t)(rowBase + row) * lda + (kloc + gc * 8),
                       Al + (size_t)(wave * 32 + ii * 8) * 64);
            }
        } else {
#pragma unroll
            for (int ii = 0; ii < 4; ++ii) {
                const int row = rw + ii * 8;
                const int gc = lch ^ (row & 7);
                const int grow = rowBase + row;
                uint4 v = make_uint4(0u, 0u, 0u, 0u);
                if (grow < M) v = *(const uint4*)(As + (size_t)grow * lda + (kloc + gc * 8));
                *(uint4*)(Al + (size_t)row * 64 + lch * 8) = v;
            }
        }
        __syncthreads();
#pragma unroll
        for (int kk = 0; kk < 2; ++kk) {
            const int gcq = kk * 4 + quad;
            short8 af[4], bfr[4];
#pragma unroll
            for (int i = 0; i < 4; ++i) {
                const int row = wr + i * 16 + l15;
                af[i] = *(const short8*)(Al + (size_t)row * 64 + ((gcq ^ (row & 7)) * 8));
            }
#pragma unroll
            for (int j = 0; j < 4; ++j) {
                const int row = wc + j * 16 + l15;
                bfr[j] = *(const short8*)(Bl + (size_t)row * 64 + ((gcq ^ (row & 7)) * 8));
            }
#pragma unroll
            for (int i = 0; i < 4; ++i)
#pragma unroll
                for (int j = 0; j < 4; ++j)
                    acc[i][j] = __builtin_amdgcn_mfma_f32_16x16x32_bf16(af[i], bfr[j], acc[i][j], 0, 0, 0);
        }
        __syncthreads();
    }

    // per-block column stats
#pragma unroll
    for (int j = 0; j < 4; ++j) {
        float s = 0.f, q = 0.f;
#pragma unroll
        for (int i = 0; i < 4; ++i)
#pragma unroll
            for (int r = 0; r < 4; ++r) {
                float v = acc[i][j][r];
                s += v; q += v * v;
            }
        s += __shfl_down(s, 32); s += __shfl_down(s, 16);
        q += __shfl_down(q, 32); q += __shfl_down(q, 16);
        if (lane < 16) {
            Ssum[wr >> 6][wc + j * 16 + l15] = s;
            Ssq[wr >> 6][wc + j * 16 + l15] = q;
        }
    }
    __syncthreads();
    if (t < 128) {
        const size_t bid = (size_t)by * GEMM_BX + bx;
        statpart[bid * 256 + t] = Ssum[0][t] + Ssum[1][t];
        statpart[bid * 256 + 128 + t] = Ssq[0][t] + Ssq[1][t];
    }
    gemm_write(acc, C, M, bx, by);

    // last active block folds k_statbn (removes a dispatch)
    __threadfence();
    __syncthreads();
    if (t == 0) lastflag = (atomicAdd(ticket, 1) == 2 * GEMM_BX - 1) ? 1 : 0;
    __syncthreads();
    if (lastflag) {
        __threadfence();
        const int c = t;                          // 0..255
        const size_t base2 = (size_t)(c >> 7) * GEMM_BX;
        const int off = c & 127;
        float s0 = 0.f, s1 = 0.f, q0 = 0.f, q1 = 0.f;
        for (int b2 = 0; b2 + 2 <= GEMM_BX; b2 += 2) {
            s0 += statpart[(base2 + b2) * 256 + off];
            q0 += statpart[(base2 + b2) * 256 + 128 + off];
            s1 += statpart[(base2 + b2 + 1) * 256 + off];
            q1 += statpart[(base2 + b2 + 1) * 256 + 128 + off];
        }
        // GEMM_BX=782 even -> loop exact
        float s = s0 + s1, q = q0 + q1;
        float mu = s * invN;
        float var = q * invN - mu * mu;
        float k2 = gg[c] * rsqrtf(var + 1e-5f);
        sc[c] = k2;
        sh[c] = beta[c] - mu * k2;
    }
}

// ---------- h_next = relu(C*sc+sh) + identity (+res_b); fp8 copy; opt dot + pool fold ----
__global__ __launch_bounds__(256) void k_finalize2(
    const u16* __restrict__ Cb, const u16* __restrict__ iden,
    const float* __restrict__ sc, const float* __restrict__ sh,
    const float* __restrict__ resb, const float* __restrict__ w,
    u16* __restrict__ hout, unsigned char* __restrict__ q8out,
    float* __restrict__ nodedot,
    const int* __restrict__ gptr, const float* __restrict__ lb,
    float* __restrict__ gout, int* __restrict__ ticket) {
    __shared__ int lastflag;
    const int i = blockIdx.x * 256 + threadIdx.x;
    const size_t base = (size_t)i * 32;
    const int c0 = (i & 7) * 32;
    const uint4* cp = (const uint4*)(Cb + base);
    const uint4* ip = (const uint4*)(iden + base);
    uint4 cv[4], iv[4];
#pragma unroll
    for (int q = 0; q < 4; ++q) cv[q] = cp[q];
#pragma unroll
    for (int q = 0; q < 4; ++q) iv[q] = ip[q];

    float dot = 0.f;
    unsigned int qa[8];
#pragma unroll
    for (int q = 0; q < 4; ++q) {
        float cf[8], df[8];
        up8(cv[q], cf); up8(iv[q], df);
        const float4 s0 = ((const float4*)(sc + c0 + q * 8))[0];
        const float4 s1 = ((const float4*)(sc + c0 + q * 8))[1];
        const float4 h0 = ((const float4*)(sh + c0 + q * 8))[0];
        const float4 h1 = ((const float4*)(sh + c0 + q * 8))[1];
        float scf[8] = {s0.x, s0.y, s0.z, s0.w, s1.x, s1.y, s1.z, s1.w};
        float shf[8] = {h0.x, h0.y, h0.z, h0.w, h1.x, h1.y, h1.z, h1.w};
        float rbf[8] = {0.f, 0.f, 0.f, 0.f, 0.f, 0.f, 0.f, 0.f};
        if (resb) {
            const float4 r0 = ((const float4*)(resb + c0 + q * 8))[0];
            const float4 r1 = ((const float4*)(resb + c0 + q * 8))[1];
            rbf[0] = r0.x; rbf[1] = r0.y; rbf[2] = r0.z; rbf[3] = r0.w;
            rbf[4] = r1.x; rbf[5] = r1.y; rbf[6] = r1.z; rbf[7] = r1.w;
        }
        float o[8];
#pragma unroll
        for (int e = 0; e < 8; ++e) {
            float v = cf[e] * scf[e] + shf[e];
            o[e] = fmaxf(v, 0.f) + df[e] + rbf[e];
        }
        if (q8out) {
            unsigned int wlo = __builtin_amdgcn_cvt_pk_fp8_f32(o[0], o[1], 0, false);
            wlo = __builtin_amdgcn_cvt_pk_fp8_f32(o[2], o[3], wlo, true);
            unsigned int whi = __builtin_amdgcn_cvt_pk_fp8_f32(o[4], o[5], 0, false);
            whi = __builtin_amdgcn_cvt_pk_fp8_f32(o[6], o[7], whi, true);
            qa[q * 2] = wlo; qa[q * 2 + 1] = whi;
        }
        if (nodedot) {
            const float4 w0 = ((const float4*)(w + c0 + q * 8))[0];
            const float4 w1 = ((const float4*)(w + c0 + q * 8))[1];
            dot += o[0] * w0.x + o[1] * w0.y + o[2] * w0.z + o[3] * w0.w
                 + o[4] * w1.x + o[5] * w1.y + o[6] * w1.z + o[7] * w1.w;
        }
        if (hout) {
            uint4* op = (uint4*)(hout + base);
            op[q] = make_uint4(pk2(o[0], o[1]), pk2(o[2], o[3]), pk2(o[4], o[5]), pk2(o[6], o[7]));
        }
    }
    if (q8out) {
        *(uint4*)(q8out + base) = make_uint4(qa[0], qa[1], qa[2], qa[3]);
        *(uint4*)(q8out + base + 16) = make_uint4(qa[4], qa[5], qa[6], qa[7]);
    }
    if (nodedot) {
        dot += __shfl_down(dot, 4);
        dot += __shfl_down(dot, 2);
        dot += __shfl_down(dot, 1);
        if ((threadIdx.x & 7) == 0) nodedot[i >> 3] = dot;
        // last block folds k_pool (removes a dispatch)
        __threadfence();
        __syncthreads();
        if (threadIdx.x == 0)
            lastflag = (atomicAdd(ticket, 1) == (N_NODESC * HDIM / 32 / 256) - 1) ? 1 : 0;
        __syncthreads();
        if (lastflag) {
            __threadfence();
            const int g = threadIdx.x;            // 0..255 graphs
            const int r0 = gptr[g], r1 = gptr[g + 1];
            float sA = 0.f, sB = 0.f;
            int k = r0;
            for (; k + 2 <= r1; k += 2) { sA += nodedot[k]; sB += nodedot[k + 1]; }
            if (k < r1) sA += nodedot[k];
            int c = r1 - r0; if (c < 1) c = 1;
            gout[g] = (sA + sB) / (float)c + lb[0];
        }
    }
}

extern "C" void kernel_launch(void* const* d_in, const int* in_sizes, int n_in,
                              void* d_out, int out_size, void* d_ws, size_t ws_size,
                              hipStream_t stream) {
    const float* x     = (const float*)d_in[0];
    const int*   ei    = (const int*)d_in[1];
    const int*   batch = (const int*)d_in[2];
    const float* Wl1 = (const float*)d_in[3];
    const float* Wr1 = (const float*)d_in[5];
    const float* g1  = (const float*)d_in[6];
    const float* be1 = (const float*)d_in[7];
    const float* Wl2 = (const float*)d_in[8];
    const float* Wr2 = (const float*)d_in[10];
    const float* g2  = (const float*)d_in[11];
    const float* be2 = (const float*)d_in[12];
    const float* Wl3 = (const float*)d_in[13];
    const float* Wr3 = (const float*)d_in[15];
    const float* g3  = (const float*)d_in[16];
    const float* be3 = (const float*)d_in[17];
    const float* Wl4 = (const float*)d_in[18];
    const float* Wr4 = (const float*)d_in[20];
    const float* g4  = (const float*)d_in[21];
    const float* be4 = (const float*)d_in[22];
    const float* resW = (const float*)d_in[23];
    const float* resb = (const float*)d_in[24];
    const float* linW = (const float*)d_in[25];
    const float* linb = (const float*)d_in[26];
    float* out = (float*)d_out;

    char* p = (char*)d_ws;
    auto carve = [&](size_t bytes) -> char* {
        char* r = p;
        p += (bytes + 255) & ~(size_t)255;
        return r;
    };
    int*   cptr    = (int*)carve((size_t)(N_NODESC + 1) * 4);
    float* dinv    = (float*)carve((size_t)N_NODESC * 4);
    int*   gptr    = (int*)carve((N_GRAPHSC + 1) * 4);
    float* nodedot = (float*)carve((size_t)N_NODESC * 4);
    float* statpart= (float*)carve((size_t)GEMM_NBLK * 256 * 4);
    float* scale   = (float*)carve(256 * 4);
    float* shift   = (float*)carve(256 * 4);
    int*   tickets = (int*)carve(16 * 4);
    int*   bhist   = (int*)carve((size_t)RX_NBLK * RX_NBUCKET * 4);
    int*   btot    = (int*)carve(RX_NBUCKET * 4);
    int*   bex     = (int*)carve((RX_NBUCKET + 1) * 4);
    int*   adj     = (int*)carve((size_t)N_EDGESC * 4);
    u16*   Wt1     = (u16*)carve(256 * 256 * 2);
    u16*   Wt2     = (u16*)carve(256 * 512 * 2);
    u16*   Wt3     = (u16*)carve(256 * 512 * 2);
    u16*   Wt4     = (u16*)carve(256 * 512 * 2);
    u16*   Rt      = (u16*)carve(256 * 128 * 2);
    u16*   xb      = (u16*)carve((size_t)N_NODESC * F_INC * 2);
    u16*   hA      = (u16*)carve((size_t)N_NODESC * HDIM * 2);
    u16*   hB      = (u16*)carve((size_t)N_NODESC * HDIM * 2);
    u16*   agg     = (u16*)carve((size_t)N_NODESC * HDIM * 2);
    u16*   Cb      = (u16*)carve((size_t)N_NODESC * HDIM * 2);
    unsigned char* q8 = (unsigned char*)carve((size_t)N_NODESC * HDIM); // fp8 node-major

    // CSR-build temporary aliases buffers dead during the build:
    int2* ebuf = (int2*)Cb;                  // dead before layer-1 gemm writes Cb
    unsigned char* xb8 = q8;                 // x fp8; dead before finalize(1) overwrites q8

    const int* srcp = ei;
    const int* dstp = ei + N_EDGESC;

    // fused prep: 5 weight transposes + x dual-convert + ticket reset (8170 blocks)
    k_prep<<<8170, 256, 0, stream>>>(Wl1, Wr1, Wl2, Wr2, Wl3, Wr3, Wl4, Wr4, resW, x,
                                     Wt1, Wt2, Wt3, Wt4, Rt, xb, xb8, tickets);

    // graph structure: bucketed counting sort, LDS atomics only
    k_rxcount<<<RX_NBLK, 256, 0, stream>>>(dstp, bhist);
    k_rxscan1<<<RX_NBUCKET, 64, 0, stream>>>(bhist, btot);
    k_rxscan2<<<1, 256, 0, stream>>>(btot, bex, cptr, batch, gptr);
    k_rxscatter<<<RX_NBLK, 256, 0, stream>>>(srcp, dstp, bhist, bex, ebuf);
    k_rxcsr<<<RX_NBUCKET, 256, 0, stream>>>(ebuf, bex, cptr, dinv, adj);

    const float invN = 1.0f / (float)N_NODESC;
    const int finBlocks = N_NODESC * HDIM / 32 / 256;  // 3125, exact

    // ---- layer 1: agg<128> fused with free res GEMM (xb@Rt -> hB) ----
    k_agg1res<<<3125 + GEMM_PAD, 256, 0, stream>>>(
        xb8, cptr, adj, dinv, agg, N_NODESC, xb, Rt, hB, N_NODESC);
    k_gemm<<<GEMM_PAD, 256, 0, stream>>>(agg, 128, xb, 128, Wt1, Cb, N_NODESC, statpart,
                                         g1, be1, scale, shift, invN, tickets + 0);
    k_finalize2<<<finBlocks, 256, 0, stream>>>(Cb, hB, scale, shift, resb, nullptr,
                                               hA, q8, nullptr, nullptr, nullptr, nullptr, nullptr);

    // ---- layer 2 ----
    k_aggregate5<256><<<6250, 256, 0, stream>>>(q8, cptr, adj, dinv, agg, N_NODESC);
    k_gemm<<<GEMM_PAD, 256, 0, stream>>>(agg, 256, hA, 256, Wt2, Cb, N_NODESC, statpart,
                                         g2, be2, scale, shift, invN, tickets + 1);
    k_finalize2<<<finBlocks, 256, 0, stream>>>(Cb, hA, scale, shift, nullptr, nullptr,
                                               hB, q8, nullptr, nullptr, nullptr, nullptr, nullptr);

    // ---- layer 3 ----
    k_aggregate5<256><<<6250, 256, 0, stream>>>(q8, cptr, adj, dinv, agg, N_NODESC);
    k_gemm<<<GEMM_PAD, 256, 0, stream>>>(agg, 256, hB, 256, Wt3, Cb, N_NODESC, statpart,
                                         g3, be3, scale, shift, invN, tickets + 2);
    k_finalize2<<<finBlocks, 256, 0, stream>>>(Cb, hB, scale, shift, nullptr, nullptr,
                                               hA, q8, nullptr, nullptr, nullptr, nullptr, nullptr);

    // ---- layer 4: finalize emits nodedot, skips dead hout, folds pool ----
    k_aggregate5<256><<<6250, 256, 0, stream>>>(q8, cptr, adj, dinv, agg, N_NODESC);
    k_gemm<<<GEMM_PAD, 256, 0, stream>>>(agg, 256, hA, 256, Wt4, Cb, N_NODESC, statpart,
                                         g4, be4, scale, shift, invN, tickets + 3);
    k_finalize2<<<finBlocks, 256, 0, stream>>>(Cb, hA, scale, shift, nullptr, linW,
                                               nullptr, nullptr, nodedot, gptr, linb, out, tickets + 4);
}

// Round 8
// 837.003 us; speedup vs baseline: 2.5236x; 2.5236x over previous
//
#include <hip/hip_runtime.h>

typedef unsigned short u16;
typedef __attribute__((ext_vector_type(8))) short short8;
typedef __attribute__((ext_vector_type(4))) float floatx4;
typedef __attribute__((ext_vector_type(2))) float floatx2;

#define N_NODESC 100000
#define N_EDGESC 1600000
#define N_GRAPHSC 256
#define F_INC 128
#define HDIM 256
#define GEMM_BX 782
#define GEMM_NBLK (GEMM_BX * 2)
#define GEMM_PAD 1568                  // 16*98 paired-swizzle launch (4 idle)
#define RX_NBLK 512
#define RX_EPB (N_EDGESC / RX_NBLK)   // 3125 exact
#define RX_NBUCKET 196                 // ceil(100000/512)
#define AGG1_NBLK 3125

// async global->LDS DMA, 16B per lane, dest = wave-uniform base + lane*16
#define GLDS16(g, l) __builtin_amdgcn_global_load_lds( \
    (const __attribute__((address_space(1))) unsigned int*)(g), \
    (__attribute__((address_space(3))) unsigned int*)(l), 16, 0, 0)

__device__ __forceinline__ float bf2f(u16 u) {
    union { unsigned int i; float f; } v; v.i = ((unsigned int)u) << 16; return v.f;
}
__device__ __forceinline__ u16 f2bf(float f) {
    union { float f; unsigned int i; } v; v.f = f;
    unsigned int b = v.i;
    b += 0x7fffu + ((b >> 16) & 1u);
    return (u16)(b >> 16);
}
__device__ __forceinline__ void up8(uint4 v, float* f) {
    f[0] = bf2f((u16)(v.x & 0xffff)); f[1] = bf2f((u16)(v.x >> 16));
    f[2] = bf2f((u16)(v.y & 0xffff)); f[3] = bf2f((u16)(v.y >> 16));
    f[4] = bf2f((u16)(v.z & 0xffff)); f[5] = bf2f((u16)(v.z >> 16));
    f[6] = bf2f((u16)(v.w & 0xffff)); f[7] = bf2f((u16)(v.w >> 16));
}
__device__ __forceinline__ unsigned int pk2(float a, float b) {
    return (unsigned int)f2bf(a) | ((unsigned int)f2bf(b) << 16);
}
// accumulate 16 fp8(e4m3) from uint4 into 8 packed float2 accumulators (v_pk_add_f32)
__device__ __forceinline__ void accv(uint4 v, floatx2* a) {
    a[0] += __builtin_amdgcn_cvt_pk_f32_fp8(v.x, false);
    a[1] += __builtin_amdgcn_cvt_pk_f32_fp8(v.x, true);
    a[2] += __builtin_amdgcn_cvt_pk_f32_fp8(v.y, false);
    a[3] += __builtin_amdgcn_cvt_pk_f32_fp8(v.y, true);
    a[4] += __builtin_amdgcn_cvt_pk_f32_fp8(v.z, false);
    a[5] += __builtin_amdgcn_cvt_pk_f32_fp8(v.z, true);
    a[6] += __builtin_amdgcn_cvt_pk_f32_fp8(v.w, false);
    a[7] += __builtin_amdgcn_cvt_pk_f32_fp8(v.w, true);
}

// ---------- fused prep: all 5 weight transposes + x dual-convert in ONE launch ----------
__device__ __forceinline__ void wcat_one(const float* __restrict__ Wl,
                                         const float* __restrict__ Wr,
                                         int K1, int K, u16* __restrict__ out, int idx) {
    int c = idx / K, k = idx - c * K;
    float v = (k < K1) ? Wl[k * 256 + c] : Wr[(k - K1) * 256 + c];
    out[idx] = f2bf(v);
}
__global__ __launch_bounds__(256) void k_prep(
    const float* __restrict__ Wl1, const float* __restrict__ Wr1,
    const float* __restrict__ Wl2, const float* __restrict__ Wr2,
    const float* __restrict__ Wl3, const float* __restrict__ Wr3,
    const float* __restrict__ Wl4, const float* __restrict__ Wr4,
    const float* __restrict__ resW, const float* __restrict__ x,
    u16* __restrict__ Wt1, u16* __restrict__ Wt2, u16* __restrict__ Wt3,
    u16* __restrict__ Wt4, u16* __restrict__ Rt,
    u16* __restrict__ xb, unsigned char* __restrict__ xb8) {
    const int b = blockIdx.x;
    const int t = threadIdx.x;
    if (b < 256) {                       // Wt1: 256x256
        wcat_one(Wl1, Wr1, 128, 256, Wt1, b * 256 + t);
    } else if (b < 768) {                // Wt2: 256x512
        wcat_one(Wl2, Wr2, 256, 512, Wt2, (b - 256) * 256 + t);
    } else if (b < 1280) {               // Wt3
        wcat_one(Wl3, Wr3, 256, 512, Wt3, (b - 768) * 256 + t);
    } else if (b < 1792) {               // Wt4
        wcat_one(Wl4, Wr4, 256, 512, Wt4, (b - 1280) * 256 + t);
    } else if (b < 1920) {               // Rt: 256x128 (K1=K=128, Wr never read)
        wcat_one(resW, resW, 128, 128, Rt, (b - 1792) * 256 + t);
    } else {                             // f2both: 6250 blocks exact
        const int i = (b - 1920) * 256 + t;
        float4 v0 = ((const float4*)x)[2 * i];
        float4 v1 = ((const float4*)x)[2 * i + 1];
        ((uint4*)xb)[i] = make_uint4(pk2(v0.x, v0.y), pk2(v0.z, v0.w),
                                     pk2(v1.x, v1.y), pk2(v1.z, v1.w));
        unsigned int wlo = __builtin_amdgcn_cvt_pk_fp8_f32(v0.x, v0.y, 0, false);
        wlo = __builtin_amdgcn_cvt_pk_fp8_f32(v0.z, v0.w, wlo, true);
        unsigned int whi = __builtin_amdgcn_cvt_pk_fp8_f32(v1.x, v1.y, 0, false);
        whi = __builtin_amdgcn_cvt_pk_fp8_f32(v1.z, v1.w, whi, true);
        ((uint2*)xb8)[i] = make_uint2(wlo, whi);
    }
}

// ========== CSR build via bucketed counting sort — LDS atomics only ==========
__global__ __launch_bounds__(256) void k_rxcount(const int* __restrict__ dst,
                                                 int* __restrict__ bhist) {
    __shared__ int h[RX_NBUCKET];
    for (int i = threadIdx.x; i < RX_NBUCKET; i += 256) h[i] = 0;
    __syncthreads();
    const int e0 = blockIdx.x * RX_EPB;
    for (int e = e0 + threadIdx.x; e < e0 + RX_EPB; e += 256)
        atomicAdd(&h[dst[e] >> 9], 1);
    __syncthreads();
    for (int i = threadIdx.x; i < RX_NBUCKET; i += 256)
        bhist[blockIdx.x * RX_NBUCKET + i] = h[i];
}

__global__ void k_rxscan1(int* __restrict__ bhist, int* __restrict__ btot) {
    const int k = blockIdx.x;   // bucket
    const int t = threadIdx.x;  // 0..63
    int v[RX_NBLK / 64];
    int s = 0;
#pragma unroll
    for (int i = 0; i < RX_NBLK / 64; ++i) {
        v[i] = bhist[(t * (RX_NBLK / 64) + i) * RX_NBUCKET + k];
        s += v[i];
    }
    int incl = s;
#pragma unroll
    for (int off = 1; off < 64; off <<= 1) {
        int u = __shfl_up(incl, off);
        if (t >= off) incl += u;
    }
    int run = incl - s;  // exclusive
#pragma unroll
    for (int i = 0; i < RX_NBLK / 64; ++i) {
        bhist[(t * (RX_NBLK / 64) + i) * RX_NBUCKET + k] = run;
        run += v[i];
    }
    if (t == 63) btot[k] = run;
}

__global__ void k_rxscan2(const int* __restrict__ btot, int* __restrict__ bex,
                          int* __restrict__ cptr, const int* __restrict__ batch,
                          int* __restrict__ gptr) {
    __shared__ int ts[256];
    int t = threadIdx.x;
    int v = (t < RX_NBUCKET) ? btot[t] : 0;
    ts[t] = v;
    __syncthreads();
    for (int off = 1; off < 256; off <<= 1) {
        int u = (t >= off) ? ts[t - off] : 0;
        __syncthreads();
        ts[t] += u;
        __syncthreads();
    }
    if (t < RX_NBUCKET) bex[t] = ts[t] - v;
    if (t == RX_NBUCKET - 1) bex[RX_NBUCKET] = ts[t];
    if (t == 0) cptr[N_NODESC] = N_EDGESC;
    {
        int lo = 0, hi = N_NODESC;
        while (lo < hi) {
            int mid = (lo + hi) >> 1;
            if (batch[mid] < t) lo = mid + 1; else hi = mid;
        }
        gptr[t] = lo;
        if (t == 0) gptr[N_GRAPHSC] = N_NODESC;
    }
}

__global__ __launch_bounds__(256) void k_rxscatter(
    const int* __restrict__ src, const int* __restrict__ dst,
    const int* __restrict__ bhist, const int* __restrict__ bex,
    int2* __restrict__ ebuf) {
    __shared__ int lb[RX_NBUCKET];
    for (int i = threadIdx.x; i < RX_NBUCKET; i += 256)
        lb[i] = bex[i] + bhist[blockIdx.x * RX_NBUCKET + i];
    __syncthreads();
    const int e0 = blockIdx.x * RX_EPB;
    for (int e = e0 + threadIdx.x; e < e0 + RX_EPB; e += 256) {
        int d = dst[e];
        int s = src[e];
        int pos = atomicAdd(&lb[d >> 9], 1);
        ebuf[pos] = make_int2(s, d);
    }
}

__global__ __launch_bounds__(256) void k_rxcsr(
    const int2* __restrict__ ebuf, const int* __restrict__ bex,
    int* __restrict__ cptr, float* __restrict__ dinv, int* __restrict__ adj) {
    __shared__ int cnt[512];
    __shared__ int excl[512];
    __shared__ int ts[256];
    const int k = blockIdx.x;
    const int nb0 = k * 512;
    const int ebase = bex[k], eend = bex[k + 1];
    const int t = threadIdx.x;
    for (int i = t; i < 512; i += 256) cnt[i] = 0;
    __syncthreads();
    for (int e = ebase + t; e < eend; e += 256)
        atomicAdd(&cnt[ebuf[e].y - nb0], 1);
    __syncthreads();
    {
        int c0 = cnt[2 * t], c1 = cnt[2 * t + 1];
        int ms = c0 + c1;
        ts[t] = ms;
        __syncthreads();
        for (int off = 1; off < 256; off <<= 1) {
            int u = (t >= off) ? ts[t - off] : 0;
            __syncthreads();
            ts[t] += u;
            __syncthreads();
        }
        int ex = ts[t] - ms;
        excl[2 * t] = ex;
        excl[2 * t + 1] = ex + c0;
        int n0 = nb0 + 2 * t, n1 = n0 + 1;
        if (n0 < N_NODESC) { cptr[n0] = ebase + ex; dinv[n0] = 1.f / (float)(c0 > 1 ? c0 : 1); }
        if (n1 < N_NODESC) { cptr[n1] = ebase + ex + c0; dinv[n1] = 1.f / (float)(c1 > 1 ? c1 : 1); }
    }
    __syncthreads();
    for (int i = t; i < 512; i += 256) cnt[i] = 0;
    __syncthreads();
    for (int e = ebase + t; e < eend; e += 256) {
        int2 p = ebuf[e];
        int dl = p.y - nb0;
        int r = atomicAdd(&cnt[dl], 1);
        adj[ebase + excl[dl] + r] = p.x;
    }
}

// ---------- aggregation core (v5, 4-deep, node-major fp8 — the proven 64us floor) ----------
template <int F>
__device__ __forceinline__ void agg_body(
    const unsigned char* __restrict__ q8, const int* __restrict__ cptr,
    const int* __restrict__ adj, const float* __restrict__ di,
    u16* __restrict__ out, int n, int blk) {
    constexpr int LPR = F / 16;       // lanes per node-row: 8 (F=128) or 16 (F=256)
    constexpr int NPW = 64 / LPR;     // nodes per wave
    const int lane = threadIdx.x & 63;
    const int li  = lane % LPR;
    const int grp = lane / LPR;
    const int node = (blk * 4 + ((int)threadIdx.x >> 6)) * NPW + grp;
    if (node >= n) return;
    const int p0 = cptr[node], p1 = cptr[node + 1];
    const float d = di[node];
    const unsigned char* base = q8 + (size_t)li * 16;
    floatx2 a[8];
#pragma unroll
    for (int e = 0; e < 8; ++e) a[e] = (floatx2){0.f, 0.f};

    int j = p0;
    for (; j + 4 <= p1; j += 4) {
        int i0 = adj[j], i1 = adj[j + 1], i2 = adj[j + 2], i3 = adj[j + 3];
        uint4 v0 = *(const uint4*)(base + (size_t)i0 * F);
        uint4 v1 = *(const uint4*)(base + (size_t)i1 * F);
        uint4 v2 = *(const uint4*)(base + (size_t)i2 * F);
        uint4 v3 = *(const uint4*)(base + (size_t)i3 * F);
        accv(v0, a); accv(v1, a); accv(v2, a); accv(v3, a);
    }
    for (; j < p1; ++j) {
        uint4 v0 = *(const uint4*)(base + (size_t)adj[j] * F);
        accv(v0, a);
    }

    uint4 o0 = make_uint4(pk2(a[0][0] * d, a[0][1] * d), pk2(a[1][0] * d, a[1][1] * d),
                          pk2(a[2][0] * d, a[2][1] * d), pk2(a[3][0] * d, a[3][1] * d));
    uint4 o1 = make_uint4(pk2(a[4][0] * d, a[4][1] * d), pk2(a[5][0] * d, a[5][1] * d),
                          pk2(a[6][0] * d, a[6][1] * d), pk2(a[7][0] * d, a[7][1] * d));
    u16* orow = out + (size_t)node * F + li * 16;
    *(uint4*)orow = o0;
    *(uint4*)(orow + 8) = o1;
}

template <int F>
__global__ __launch_bounds__(256) void k_aggregate5(
    const unsigned char* __restrict__ q8, const int* __restrict__ cptr,
    const int* __restrict__ adj, const float* __restrict__ di,
    u16* __restrict__ out, int n) {
    agg_body<F>(q8, cptr, adj, di, out, n, blockIdx.x);
}

// ---------- fused layer-1: aggregation (blocks < 3125) + residual GEMM (paired swizzle) ----
__global__ __launch_bounds__(256, 4) void k_agg1res(
    const unsigned char* __restrict__ q8s, const int* __restrict__ cptr,
    const int* __restrict__ adj, const float* __restrict__ di,
    u16* __restrict__ aggout, int n,
    const u16* __restrict__ A, const u16* __restrict__ Rt,
    u16* __restrict__ C, int M) {
    __shared__ __align__(16) u16 Al[128 * 64];
    __shared__ __align__(16) u16 Bl[128 * 64];
    if (blockIdx.x < AGG1_NBLK) {
        agg_body<128>(q8s, cptr, adj, di, aggout, n, blockIdx.x);
        return;
    }
    const int bid = blockIdx.x - AGG1_NBLK;
    const int bx = (bid >> 4) * 8 + (bid & 7);   // paired: ids d, d+8 share bx and XCD
    const int by = (bid >> 3) & 1;
    if (bx >= GEMM_BX) return;
    const int t = threadIdx.x;
    const int lane = t & 63;
    const int wave = t >> 6;
    const int wr = (wave >> 1) * 64, wc = (wave & 1) * 64;
    const int quad = lane >> 4, l15 = lane & 15;
    const int rowBase = bx * 128;
    const int colBase = by * 128;
    const bool fastA = (rowBase + 128 <= M);

    floatx4 acc[4][4];
#pragma unroll
    for (int i = 0; i < 4; ++i)
#pragma unroll
        for (int j = 0; j < 4; ++j)
            acc[i][j] = (floatx4){0.f, 0.f, 0.f, 0.f};

    const int rw = wave * 32 + (lane >> 3);
    const int lch = lane & 7;

    for (int kt = 0; kt < 128; kt += 64) {
#pragma unroll
        for (int ii = 0; ii < 4; ++ii) {
            const int row = rw + ii * 8;
            const int gc = lch ^ (row & 7);
            GLDS16(Rt + (size_t)(colBase + row) * 128 + (kt + gc * 8),
                   Bl + (size_t)(wave * 32 + ii * 8) * 64);
        }
        if (fastA) {
#pragma unroll
            for (int ii = 0; ii < 4; ++ii) {
                const int row = rw + ii * 8;
                const int gc = lch ^ (row & 7);
                GLDS16(A + (size_t)(rowBase + row) * 128 + (kt + gc * 8),
                       Al + (size_t)(wave * 32 + ii * 8) * 64);
            }
        } else {
#pragma unroll
            for (int ii = 0; ii < 4; ++ii) {
                const int row = rw + ii * 8;
                const int gc = lch ^ (row & 7);
                const int grow = rowBase + row;
                uint4 v = make_uint4(0u, 0u, 0u, 0u);
                if (grow < M) v = *(const uint4*)(A + (size_t)grow * 128 + (kt + gc * 8));
                *(uint4*)(Al + (size_t)row * 64 + lch * 8) = v;
            }
        }
        __syncthreads();
#pragma unroll
        for (int kk = 0; kk < 2; ++kk) {
            const int gcq = kk * 4 + quad;
            short8 af[4], bfr[4];
#pragma unroll
            for (int i = 0; i < 4; ++i) {
                const int row = wr + i * 16 + l15;
                af[i] = *(const short8*)(Al + (size_t)row * 64 + ((gcq ^ (row & 7)) * 8));
            }
#pragma unroll
            for (int j = 0; j < 4; ++j) {
                const int row = wc + j * 16 + l15;
                bfr[j] = *(const short8*)(Bl + (size_t)row * 64 + ((gcq ^ (row & 7)) * 8));
            }
#pragma unroll
            for (int i = 0; i < 4; ++i)
#pragma unroll
                for (int j = 0; j < 4; ++j)
                    acc[i][j] = __builtin_amdgcn_mfma_f32_16x16x32_bf16(af[i], bfr[j], acc[i][j], 0, 0, 0);
        }
        __syncthreads();
    }
#pragma unroll
    for (int i = 0; i < 4; ++i) {
#pragma unroll
        for (int r = 0; r < 4; ++r) {
            const int row = rowBase + wr + i * 16 + quad * 4 + r;
            if (row < M) {
#pragma unroll
                for (int j = 0; j < 4; ++j) {
                    const int col = colBase + wc + j * 16 + l15;
                    C[(size_t)row * HDIM + col] = f2bf(acc[i][j][r]);
                }
            }
        }
    }
}

// ---------- GEMM: paired-swizzle (A-tile L2 reuse across the two N-halves) ----------
__global__ __launch_bounds__(256, 4) void k_gemm(
    const u16* __restrict__ A1, int K1,
    const u16* __restrict__ A2, int K2,
    const u16* __restrict__ Wt,
    u16* __restrict__ C, int M, float* __restrict__ statpart) {
    const int K = K1 + K2;
    __shared__ __align__(16) u16 Al[128 * 64];
    __shared__ __align__(16) u16 Bl[128 * 64];
    __shared__ float Ssum[2][128];
    __shared__ float Ssq[2][128];
    const int id = blockIdx.x;
    const int bx = (id >> 4) * 8 + (id & 7);     // ids d and d+8 share bx AND XCD (id%8)
    const int by = (id >> 3) & 1;
    if (bx >= GEMM_BX) return;
    const int t = threadIdx.x;
    const int lane = t & 63;
    const int wave = t >> 6;
    const int wr = (wave >> 1) * 64, wc = (wave & 1) * 64;
    const int quad = lane >> 4, l15 = lane & 15;
    const int rowBase = bx * 128;
    const int colBase = by * 128;
    const bool fastA = (rowBase + 128 <= M);

    floatx4 acc[4][4];
#pragma unroll
    for (int i = 0; i < 4; ++i)
#pragma unroll
        for (int j = 0; j < 4; ++j)
            acc[i][j] = (floatx4){0.f, 0.f, 0.f, 0.f};

    const int rw = wave * 32 + (lane >> 3);
    const int lch = lane & 7;

    for (int kt = 0; kt < K; kt += 64) {
        const u16* As; int lda, kloc;
        if (kt < K1) { As = A1; lda = K1; kloc = kt; }
        else         { As = A2; lda = K2; kloc = kt - K1; }
#pragma unroll
        for (int ii = 0; ii < 4; ++ii) {
            const int row = rw + ii * 8;
            const int gc = lch ^ (row & 7);
            GLDS16(Wt + (size_t)(colBase + row) * K + (kt + gc * 8),
                   Bl + (size_t)(wave * 32 + ii * 8) * 64);
        }
        if (fastA) {
#pragma unroll
            for (int ii = 0; ii < 4; ++ii) {
                const int row = rw + ii * 8;
                const int gc = lch ^ (row & 7);
                GLDS16(As + (size_t)(rowBase + row) * lda + (kloc + gc * 8),
                       Al + (size_t)(wave * 32 + ii * 8) * 64);
            }
        } else {
#pragma unroll
            for (int ii = 0; ii < 4; ++ii) {
                const int row = rw + ii * 8;
                const int gc = lch ^ (row & 7);
                const int grow = rowBase + row;
                uint4 v = make_uint4(0u, 0u, 0u, 0u);
                if (grow < M) v = *(const uint4*)(As + (size_t)grow * lda + (kloc + gc * 8));
                *(uint4*)(Al + (size_t)row * 64 + lch * 8) = v;
            }
        }
        __syncthreads();
#pragma unroll
        for (int kk = 0; kk < 2; ++kk) {
            const int gcq = kk * 4 + quad;
            short8 af[4], bfr[4];
#pragma unroll
            for (int i = 0; i < 4; ++i) {
                const int row = wr + i * 16 + l15;
                af[i] = *(const short8*)(Al + (size_t)row * 64 + ((gcq ^ (row & 7)) * 8));
            }
#pragma unroll
            for (int j = 0; j < 4; ++j) {
                const int row = wc + j * 16 + l15;
                bfr[j] = *(const short8*)(Bl + (size_t)row * 64 + ((gcq ^ (row & 7)) * 8));
            }
#pragma unroll
            for (int i = 0; i < 4; ++i)
#pragma unroll
                for (int j = 0; j < 4; ++j)
                    acc[i][j] = __builtin_amdgcn_mfma_f32_16x16x32_bf16(af[i], bfr[j], acc[i][j], 0, 0, 0);
        }
        __syncthreads();
    }
    if (statpart) {
#pragma unroll
        for (int j = 0; j < 4; ++j) {
            float s = 0.f, q = 0.f;
#pragma unroll
            for (int i = 0; i < 4; ++i)
#pragma unroll
                for (int r = 0; r < 4; ++r) {
                    float v = acc[i][j][r];
                    s += v; q += v * v;
                }
            s += __shfl_down(s, 32); s += __shfl_down(s, 16);
            q += __shfl_down(q, 32); q += __shfl_down(q, 16);
            if (lane < 16) {
                Ssum[wr >> 6][wc + j * 16 + l15] = s;
                Ssq[wr >> 6][wc + j * 16 + l15] = q;
            }
        }
        __syncthreads();
        if (t < 128) {
            const size_t bid = (size_t)by * GEMM_BX + bx;
            statpart[bid * 256 + t] = Ssum[0][t] + Ssum[1][t];
            statpart[bid * 256 + 128 + t] = Ssq[0][t] + Ssq[1][t];
        }
    }
#pragma unroll
    for (int i = 0; i < 4; ++i) {
#pragma unroll
        for (int r = 0; r < 4; ++r) {
            const int row = rowBase + wr + i * 16 + quad * 4 + r;
            if (row < M) {
#pragma unroll
                for (int j = 0; j < 4; ++j) {
                    const int col = colBase + wc + j * 16 + l15;
                    C[(size_t)row * HDIM + col] = f2bf(acc[i][j][r]);
                }
            }
        }
    }
}

// ---------- fused stat reduce + BN scale/shift: one block per column ----------
__global__ void k_statbn(const float* __restrict__ sp, const float* __restrict__ g,
                         const float* __restrict__ beta, float* __restrict__ sc,
                         float* __restrict__ sh, float invN) {
    const int c = blockIdx.x;
    const size_t base = (size_t)(c >> 7) * GEMM_BX;
    const int off = c & 127;
    float s = 0.f, q = 0.f;
    for (int bx = threadIdx.x; bx < GEMM_BX; bx += 64) {
        s += sp[(base + bx) * 256 + off];
        q += sp[(base + bx) * 256 + 128 + off];
    }
#pragma unroll
    for (int o = 32; o > 0; o >>= 1) { s += __shfl_down(s, o); q += __shfl_down(q, o); }
    if (threadIdx.x == 0) {
        float mu = s * invN;
        float var = q * invN - mu * mu;
        float k = g[c] * rsqrtf(var + 1e-5f);
        sc[c] = k;
        sh[c] = beta[c] - mu * k;
    }
}

// ---------- h_next = relu(C*scale+shift) + identity (+res_b); fp8 copy; optional dot ----------
__global__ __launch_bounds__(256) void k_finalize2(
    const u16* __restrict__ Cb, const u16* __restrict__ iden,
    const float* __restrict__ sc, const float* __restrict__ sh,
    const float* __restrict__ resb, const float* __restrict__ w,
    u16* __restrict__ hout, unsigned char* __restrict__ q8out,
    float* __restrict__ nodedot) {
    const int i = blockIdx.x * 256 + threadIdx.x;
    const size_t base = (size_t)i * 32;
    const int c0 = (i & 7) * 32;
    const uint4* cp = (const uint4*)(Cb + base);
    const uint4* ip = (const uint4*)(iden + base);
    uint4 cv[4], iv[4];
#pragma unroll
    for (int q = 0; q < 4; ++q) cv[q] = cp[q];
#pragma unroll
    for (int q = 0; q < 4; ++q) iv[q] = ip[q];

    float dot = 0.f;
    unsigned int qa[8];
    uint4* op = (uint4*)(hout + base);
#pragma unroll
    for (int q = 0; q < 4; ++q) {
        float cf[8], df[8];
        up8(cv[q], cf); up8(iv[q], df);
        const float4 s0 = ((const float4*)(sc + c0 + q * 8))[0];
        const float4 s1 = ((const float4*)(sc + c0 + q * 8))[1];
        const float4 h0 = ((const float4*)(sh + c0 + q * 8))[0];
        const float4 h1 = ((const float4*)(sh + c0 + q * 8))[1];
        float scf[8] = {s0.x, s0.y, s0.z, s0.w, s1.x, s1.y, s1.z, s1.w};
        float shf[8] = {h0.x, h0.y, h0.z, h0.w, h1.x, h1.y, h1.z, h1.w};
        float rbf[8] = {0.f, 0.f, 0.f, 0.f, 0.f, 0.f, 0.f, 0.f};
        if (resb) {
            const float4 r0 = ((const float4*)(resb + c0 + q * 8))[0];
            const float4 r1 = ((const float4*)(resb + c0 + q * 8))[1];
            rbf[0] = r0.x; rbf[1] = r0.y; rbf[2] = r0.z; rbf[3] = r0.w;
            rbf[4] = r1.x; rbf[5] = r1.y; rbf[6] = r1.z; rbf[7] = r1.w;
        }
        float o[8];
#pragma unroll
        for (int e = 0; e < 8; ++e) {
            float v = cf[e] * scf[e] + shf[e];
            o[e] = fmaxf(v, 0.f) + df[e] + rbf[e];
        }
        if (q8out) {
            unsigned int wlo = __builtin_amdgcn_cvt_pk_fp8_f32(o[0], o[1], 0, false);
            wlo = __builtin_amdgcn_cvt_pk_fp8_f32(o[2], o[3], wlo, true);
            unsigned int whi = __builtin_amdgcn_cvt_pk_fp8_f32(o[4], o[5], 0, false);
            whi = __builtin_amdgcn_cvt_pk_fp8_f32(o[6], o[7], whi, true);
            qa[q * 2] = wlo; qa[q * 2 + 1] = whi;
        }
        if (nodedot) {
            const float4 w0 = ((const float4*)(w + c0 + q * 8))[0];
            const float4 w1 = ((const float4*)(w + c0 + q * 8))[1];
            dot += o[0] * w0.x + o[1] * w0.y + o[2] * w0.z + o[3] * w0.w
                 + o[4] * w1.x + o[5] * w1.y + o[6] * w1.z + o[7] * w1.w;
        }
        op[q] = make_uint4(pk2(o[0], o[1]), pk2(o[2], o[3]), pk2(o[4], o[5]), pk2(o[6], o[7]));
    }
    if (q8out) {
        *(uint4*)(q8out + base) = make_uint4(qa[0], qa[1], qa[2], qa[3]);
        *(uint4*)(q8out + base + 16) = make_uint4(qa[4], qa[5], qa[6], qa[7]);
    }
    if (nodedot) {
        dot += __shfl_down(dot, 4);
        dot += __shfl_down(dot, 2);
        dot += __shfl_down(dot, 1);
        if ((threadIdx.x & 7) == 0) nodedot[i >> 3] = dot;
    }
}

// ---------- readout stage 2: one block per graph, contiguous segment sum ----------
__global__ void k_pool(const float* __restrict__ nodedot, const int* __restrict__ gptr,
                       const float* __restrict__ lb, float* __restrict__ out) {
    const int g = blockIdx.x;
    const int r0 = gptr[g], r1 = gptr[g + 1];
    float s = 0.f;
    for (int i = r0 + threadIdx.x; i < r1; i += 256) s += nodedot[i];
#pragma unroll
    for (int off = 32; off > 0; off >>= 1) s += __shfl_down(s, off);
    __shared__ float red[4];
    const int wave = threadIdx.x >> 6;
    if ((threadIdx.x & 63) == 0) red[wave] = s;
    __syncthreads();
    if (threadIdx.x == 0) {
        float tot = red[0] + red[1] + red[2] + red[3];
        int c = r1 - r0; if (c < 1) c = 1;
        out[g] = tot / (float)c + lb[0];
    }
}

extern "C" void kernel_launch(void* const* d_in, const int* in_sizes, int n_in,
                              void* d_out, int out_size, void* d_ws, size_t ws_size,
                              hipStream_t stream) {
    const float* x     = (const float*)d_in[0];
    const int*   ei    = (const int*)d_in[1];
    const int*   batch = (const int*)d_in[2];
    const float* Wl1 = (const float*)d_in[3];
    const float* Wr1 = (const float*)d_in[5];
    const float* g1  = (const float*)d_in[6];
    const float* be1 = (const float*)d_in[7];
    const float* Wl2 = (const float*)d_in[8];
    const float* Wr2 = (const float*)d_in[10];
    const float* g2  = (const float*)d_in[11];
    const float* be2 = (const float*)d_in[12];
    const float* Wl3 = (const float*)d_in[13];
    const float* Wr3 = (const float*)d_in[15];
    const float* g3  = (const float*)d_in[16];
    const float* be3 = (const float*)d_in[17];
    const float* Wl4 = (const float*)d_in[18];
    const float* Wr4 = (const float*)d_in[20];
    const float* g4  = (const float*)d_in[21];
    const float* be4 = (const float*)d_in[22];
    const float* resW = (const float*)d_in[23];
    const float* resb = (const float*)d_in[24];
    const float* linW = (const float*)d_in[25];
    const float* linb = (const float*)d_in[26];
    float* out = (float*)d_out;

    char* p = (char*)d_ws;
    auto carve = [&](size_t bytes) -> char* {
        char* r = p;
        p += (bytes + 255) & ~(size_t)255;
        return r;
    };
    int*   cptr    = (int*)carve((size_t)(N_NODESC + 1) * 4);
    float* dinv    = (float*)carve((size_t)N_NODESC * 4);
    int*   gptr    = (int*)carve((N_GRAPHSC + 1) * 4);
    float* nodedot = (float*)carve((size_t)N_NODESC * 4);
    float* statpart= (float*)carve((size_t)GEMM_NBLK * 256 * 4);
    float* scale   = (float*)carve(256 * 4);
    float* shift   = (float*)carve(256 * 4);
    int*   bhist   = (int*)carve((size_t)RX_NBLK * RX_NBUCKET * 4);
    int*   btot    = (int*)carve(RX_NBUCKET * 4);
    int*   bex     = (int*)carve((RX_NBUCKET + 1) * 4);
    int*   adj     = (int*)carve((size_t)N_EDGESC * 4);
    u16*   Wt1     = (u16*)carve(256 * 256 * 2);
    u16*   Wt2     = (u16*)carve(256 * 512 * 2);
    u16*   Wt3     = (u16*)carve(256 * 512 * 2);
    u16*   Wt4     = (u16*)carve(256 * 512 * 2);
    u16*   Rt      = (u16*)carve(256 * 128 * 2);
    u16*   xb      = (u16*)carve((size_t)N_NODESC * F_INC * 2);
    u16*   hA      = (u16*)carve((size_t)N_NODESC * HDIM * 2);
    u16*   hB      = (u16*)carve((size_t)N_NODESC * HDIM * 2);
    u16*   agg     = (u16*)carve((size_t)N_NODESC * HDIM * 2);
    u16*   Cb      = (u16*)carve((size_t)N_NODESC * HDIM * 2);
    unsigned char* q8 = (unsigned char*)carve((size_t)N_NODESC * HDIM); // fp8 node-major

    // CSR-build temporary aliases buffers dead during the build:
    int2* ebuf = (int2*)Cb;                  // dead before layer-1 gemm writes Cb
    unsigned char* xb8 = q8;                 // x fp8; dead before finalize(1) overwrites q8

    const int* srcp = ei;
    const int* dstp = ei + N_EDGESC;

    // fused prep: 5 weight transposes + x dual-convert, one launch (8170 blocks)
    k_prep<<<8170, 256, 0, stream>>>(Wl1, Wr1, Wl2, Wr2, Wl3, Wr3, Wl4, Wr4, resW, x,
                                     Wt1, Wt2, Wt3, Wt4, Rt, xb, xb8);

    // graph structure: bucketed counting sort, LDS atomics only
    k_rxcount<<<RX_NBLK, 256, 0, stream>>>(dstp, bhist);
    k_rxscan1<<<RX_NBUCKET, 64, 0, stream>>>(bhist, btot);
    k_rxscan2<<<1, 256, 0, stream>>>(btot, bex, cptr, batch, gptr);
    k_rxscatter<<<RX_NBLK, 256, 0, stream>>>(srcp, dstp, bhist, bex, ebuf);
    k_rxcsr<<<RX_NBUCKET, 256, 0, stream>>>(ebuf, bex, cptr, dinv, adj);

    const float invN = 1.0f / (float)N_NODESC;
    const int finBlocks = N_NODESC * HDIM / 32 / 256;  // 3125, exact

    // ---- layer 1: agg<128> fused with free res GEMM (xb@Rt -> hB) ----
    k_agg1res<<<AGG1_NBLK + GEMM_PAD, 256, 0, stream>>>(
        xb8, cptr, adj, dinv, agg, N_NODESC, xb, Rt, hB, N_NODESC);
    k_gemm<<<GEMM_PAD, 256, 0, stream>>>(agg, 128, xb, 128, Wt1, Cb, N_NODESC, statpart);
    k_statbn<<<256, 64, 0, stream>>>(statpart, g1, be1, scale, shift, invN);
    k_finalize2<<<finBlocks, 256, 0, stream>>>(Cb, hB, scale, shift, resb, nullptr, hA, q8, nullptr);

    // ---- layer 2 ----
    k_aggregate5<256><<<6250, 256, 0, stream>>>(q8, cptr, adj, dinv, agg, N_NODESC);
    k_gemm<<<GEMM_PAD, 256, 0, stream>>>(agg, 256, hA, 256, Wt2, Cb, N_NODESC, statpart);
    k_statbn<<<256, 64, 0, stream>>>(statpart, g2, be2, scale, shift, invN);
    k_finalize2<<<finBlocks, 256, 0, stream>>>(Cb, hA, scale, shift, nullptr, nullptr, hB, q8, nullptr);

    // ---- layer 3 ----
    k_aggregate5<256><<<6250, 256, 0, stream>>>(q8, cptr, adj, dinv, agg, N_NODESC);
    k_gemm<<<GEMM_PAD, 256, 0, stream>>>(agg, 256, hB, 256, Wt3, Cb, N_NODESC, statpart);
    k_statbn<<<256, 64, 0, stream>>>(statpart, g3, be3, scale, shift, invN);
    k_finalize2<<<finBlocks, 256, 0, stream>>>(Cb, hB, scale, shift, nullptr, nullptr, hA, q8, nullptr);

    // ---- layer 4 (fused per-node dot with lin_W) ----
    k_aggregate5<256><<<6250, 256, 0, stream>>>(q8, cptr, adj, dinv, agg, N_NODESC);
    k_gemm<<<GEMM_PAD, 256, 0, stream>>>(agg, 256, hA, 256, Wt4, Cb, N_NODESC, statpart);
    k_statbn<<<256, 64, 0, stream>>>(statpart, g4, be4, scale, shift, invN);
    k_finalize2<<<finBlocks, 256, 0, stream>>>(Cb, hA, scale, shift, nullptr, linW, hB, nullptr, nodedot);

    // ---- pooled mean + lin_b ----
    k_pool<<<N_GRAPHSC, 256, 0, stream>>>(nodedot, gptr, linb, out);
}